// Round 11
// baseline (221.148 us; speedup 1.0000x reference)
//
#include <hip/hip_runtime.h>
#include <hip/hip_bf16.h>

#define NND 2048
#define BBATCH 4
#define SS 1024
#define SFZ 384
#define IFZ 256
#define HH 8
#define AA 64
#define HA 512
#define NBX 48    // x-blocks per batch (768-node capacity, 13 sigma)
#define NSPL 4    // S-splits in attention (r8 A/B: same attn time as 8, 1/3 writes)

typedef __attribute__((ext_vector_type(8))) short bf16x8;
typedef __attribute__((ext_vector_type(4))) float f32x4;

__device__ __forceinline__ unsigned short f2bf(float f) {
    union { float f; unsigned u; } a; a.f = f;
    unsigned r = a.u + 0x7fffu + ((a.u >> 16) & 1u);
    return (unsigned short)(r >> 16);
}
__device__ __forceinline__ float bf2f(unsigned short u) {
    return __uint_as_float((unsigned)u << 16);
}

__device__ __forceinline__ bf16x8 cvt8(const float* __restrict__ p) {
    const float4 f0 = *(const float4*)p;
    const float4 f1 = *(const float4*)(p + 4);
    bf16x8 o;
    o[0] = (short)f2bf(f0.x); o[1] = (short)f2bf(f0.y);
    o[2] = (short)f2bf(f0.z); o[3] = (short)f2bf(f0.w);
    o[4] = (short)f2bf(f1.x); o[5] = (short)f2bf(f1.y);
    o[6] = (short)f2bf(f1.z); o[7] = (short)f2bf(f1.w);
    return o;
}

// ---------------------------------------------------------------------------
// Kernel P: prep. Blocks 0..191: weight transposes fp32->bf16.
// Block 192: detect mask/batch dtype -> mask_f, seg.
// ---------------------------------------------------------------------------
__device__ __forceinline__ void tile_transpose(
    const float* __restrict__ src, unsigned short* __restrict__ dst,
    int K, int N, int kt, int nt, int t)
{
    __shared__ unsigned short tile[64][65];
    const int k0 = kt * 64, n0 = nt * 64;
    const int tr = t >> 6, tc = t & 63;
    #pragma unroll
    for (int r = 0; r < 16; ++r)
        tile[tr + r*4][tc] = f2bf(src[(size_t)(k0 + tr + r*4) * N + n0 + tc]);
    __syncthreads();
    #pragma unroll
    for (int r = 0; r < 16; ++r)
        dst[(size_t)(n0 + tr + r*4) * K + k0 + tc] = tile[tc][tr + r*4];
}

__global__ __launch_bounds__(256) void prep_kernel(
    const float* __restrict__ Wk, const float* __restrict__ Wv,
    const float* __restrict__ Wq, const float* __restrict__ Wg,
    const float* __restrict__ Wback,
    const void* __restrict__ mask_raw, const void* __restrict__ batch_raw,
    unsigned short* __restrict__ WkT, unsigned short* __restrict__ WvT,
    unsigned short* __restrict__ WqT, unsigned short* __restrict__ WgT,
    unsigned short* __restrict__ WbackT,
    float* __restrict__ mask_f, int* __restrict__ seg)
{
    const int bx = blockIdx.x, t = threadIdx.x;
    if (bx < 48)  { tile_transpose(Wk, WkT, SFZ, HA, bx/8, bx%8, t); return; }
    if (bx < 96)  { const int i = bx-48;  tile_transpose(Wv, WvT, SFZ, HA, i/8, i%8, t); return; }
    if (bx < 128) { const int i = bx-96;  tile_transpose(Wq, WqT, IFZ, HA, i/8, i%8, t); return; }
    if (bx < 160) { const int i = bx-128; tile_transpose(Wg, WgT, IFZ, HA, i/8, i%8, t); return; }
    if (bx < 192) { const int i = bx-160; tile_transpose(Wback, WbackT, HA, IFZ, i/4, i%4, t); return; }
    __shared__ int fl[4];
    __shared__ int fb;
    __shared__ int cnt[4];
    if (t < 4) { fl[t] = 0; cnt[t] = 0; }
    if (t == 0) fb = 0;
    __syncthreads();
    const unsigned char*  mb = (const unsigned char*)mask_raw;
    const unsigned short* mh = (const unsigned short*)mask_raw;
    const unsigned int*   mw = (const unsigned int*)mask_raw;
    int f0 = 0, f1 = 0, f2 = 0, f3 = 0;
    for (int i = t; i < 2048; i += 256) {
        unsigned short h = mh[i];
        if (h == 0x3f80u) f0 = 1;
        if ((i & 1) == 0 && h != 0) f1 = 1;
    }
    for (int i = t; i < 4096; i += 256)
        if ((i & 3) != 0 && mb[i] != 0) f2 = 1;
    for (int i = t; i < 1024; i += 256)
        if ((i & 1) != 0 && mw[i] != 0) f3 = 1;
    const int* bw = (const int*)batch_raw;
    int f4 = 0;
    for (int i = t + 1; i < 2048; i += 256)
        if (bw[i] < bw[i-1]) f4 = 1;
    if (f0) atomicOr(&fl[0], 1);
    if (f1) atomicOr(&fl[1], 1);
    if (f2) atomicOr(&fl[2], 1);
    if (f3) atomicOr(&fl[3], 1);
    if (f4) atomicOr(&fb, 1);
    __syncthreads();
    int mode;
    if (fl[0])      mode = fl[1] ? 1 : 0;
    else if (fl[2]) mode = 2;
    else if (fl[3]) mode = 3;
    else            mode = 4;
    for (int s = t; s < BBATCH*SS; s += 256) {
        int m;
        switch (mode) {
            case 0:  m = (mw[s]   != 0); break;
            case 1:  m = (mh[s]   != 0); break;
            case 2:  m = (mb[s]   != 0); break;
            case 3:  m = (mw[s]   != 0); break;
            default: m = (mw[2*s] != 0); break;
        }
        mask_f[s] = m ? 1.0f : 0.0f;
    }
    const int b64 = fb;
    for (int i = t; i < NND; i += 256) {
        const int bv = (b64 ? bw[2*i] : bw[i]) & 3;
        atomicAdd(&cnt[bv], 1);
    }
    __syncthreads();
    if (t == 0) {
        int s = 0;
        for (int b = 0; b < 4; ++b) { seg[2*b] = s; s += cnt[b]; seg[2*b+1] = s; }
    }
}

// ---------------------------------------------------------------------------
// Kernel 1: fused MFMA projections. 1536 blocks:
// [0,1024): k/v, col-halves. sub=bx&3: tensor=sub>>1 (0=k,1=v), chalf=sub&1.
//           k head-major k_blk[b][h][s][64]; v transposed in-kernel to vT.
// [1024,1536): q/gate (as before).
// ---------------------------------------------------------------------------
__global__ __launch_bounds__(256) void proj_mfma(
    const float* __restrict__ emb, const float* __restrict__ x,
    const unsigned short* __restrict__ WkT, const unsigned short* __restrict__ WvT,
    const unsigned short* __restrict__ WqT, const unsigned short* __restrict__ WgT,
    const float* __restrict__ bg,
    unsigned short* __restrict__ k_blk, unsigned short* __restrict__ vT_bf,
    unsigned short* __restrict__ q_bf, float* __restrict__ gate_ws)
{
    __shared__ unsigned short v_l[16][520];   // 16.6 KB (v-blocks only)
    const int t = threadIdx.x, w = t >> 6, lane = t & 63;
    const int m16 = lane & 15, quad = lane >> 4;
    const int bx = blockIdx.x;
    if (bx < 1024) {
        const int r0 = (bx >> 2) * 16;
        const int sub = bx & 3;
        const int tensor = sub >> 1, chalf = sub & 1;
        const int b = r0 >> 10, srow = r0 & (SS - 1);
        const float* ap = emb + (size_t)(r0 + m16) * SFZ + quad * 8;
        bf16x8 af[12];
        #pragma unroll
        for (int j = 0; j < 12; ++j) af[j] = cvt8(ap + j * 32);
        if (tensor == 0) {
            #pragma unroll
            for (int nt = 0; nt < 4; ++nt) {
                const int n0 = chalf * 256 + w * 64 + nt * 16;
                const unsigned short* bp = WkT + (size_t)(n0 + m16) * SFZ + quad * 8;
                f32x4 d = (f32x4){0.f, 0.f, 0.f, 0.f};
                #pragma unroll
                for (int j = 0; j < 12; ++j)
                    d = __builtin_amdgcn_mfma_f32_16x16x32_bf16(af[j], *(const bf16x8*)(bp + j * 32), d, 0, 0, 0);
                const int head = n0 >> 6, coff = (n0 & 63) + m16;
                unsigned short* kb = k_blk + (((size_t)(b * HH + head)) * SS) * 64 + coff;
                #pragma unroll
                for (int r = 0; r < 4; ++r)
                    kb[(size_t)(srow + quad * 4 + r) * 64] = f2bf(d[r]);
            }
        } else {
            #pragma unroll
            for (int nt = 0; nt < 4; ++nt) {
                const int n0 = chalf * 256 + w * 64 + nt * 16;
                const unsigned short* bp = WvT + (size_t)(n0 + m16) * SFZ + quad * 8;
                f32x4 d = (f32x4){0.f, 0.f, 0.f, 0.f};
                #pragma unroll
                for (int j = 0; j < 12; ++j)
                    d = __builtin_amdgcn_mfma_f32_16x16x32_bf16(af[j], *(const bf16x8*)(bp + j * 32), d, 0, 0, 0);
                #pragma unroll
                for (int r = 0; r < 4; ++r)
                    v_l[quad * 4 + r][n0 + m16] = f2bf(d[r]);
            }
            __syncthreads();
            // vT[b][c][srow..srow+16): column gather from LDS, 2x16B stores
            {
                const int c = chalf * 256 + t;
                unsigned short tmp[16];
                #pragma unroll
                for (int s = 0; s < 16; ++s) tmp[s] = v_l[s][c];
                unsigned short* dst = vT_bf + ((size_t)b * HA + c) * SS + srow;
                *(uint4*)dst       = ((const uint4*)tmp)[0];
                *(uint4*)(dst + 8) = ((const uint4*)tmp)[1];
            }
        }
    } else {
        const int i = bx - 1024;
        const int r0 = (i >> 2) * 16;
        const int tensor = (i & 3) >> 1, half = i & 1;
        const unsigned short* Wt = tensor ? WgT : WqT;
        const float* ap = x + (size_t)(r0 + m16) * IFZ + quad * 8;
        bf16x8 af[8];
        #pragma unroll
        for (int j = 0; j < 8; ++j) af[j] = cvt8(ap + j * 32);
        #pragma unroll
        for (int nt = 0; nt < 4; ++nt) {
            const int n0 = half * 256 + w * 64 + nt * 16;
            const unsigned short* bp = Wt + (size_t)(n0 + m16) * IFZ + quad * 8;
            f32x4 d = (f32x4){0.f, 0.f, 0.f, 0.f};
            #pragma unroll
            for (int j = 0; j < 8; ++j)
                d = __builtin_amdgcn_mfma_f32_16x16x32_bf16(af[j], *(const bf16x8*)(bp + j * 32), d, 0, 0, 0);
            if (tensor == 0) {
                #pragma unroll
                for (int r = 0; r < 4; ++r)
                    q_bf[(size_t)(r0 + quad * 4 + r) * HA + n0 + m16] = f2bf(d[r]);
            } else {
                const float bgv = bg[n0 + m16];
                #pragma unroll
                for (int r = 0; r < 4; ++r)
                    gate_ws[(size_t)(r0 + quad * 4 + r) * HA + n0 + m16] =
                        1.f / (1.f + __expf(-(d[r] + bgv)));
            }
        }
    }
}

// ---------------------------------------------------------------------------
// Kernel 3: MFMA flash attention, barrier-free, fused logits, online softmax.
// 1536 blocks, XCD-batch affinity; z = (hz(2), split(4)); 2 chunks of 128 s.
// hz==0/w==0 wave also computes h1 scores and writes h0+h1 raw logits.
// Coalesced epilogue: facc restaged bf16 through P_lds -> 2x16B stores.
// ---------------------------------------------------------------------------
__global__ __launch_bounds__(256) void attn_kernel(
    const unsigned short* __restrict__ k_blk, const unsigned short* __restrict__ vT_bf,
    const unsigned short* __restrict__ q_bf, const float* __restrict__ mask_f,
    const int* __restrict__ seg, unsigned short* __restrict__ part_O,
    float2* __restrict__ part_ml, float* __restrict__ out_logits)
{
    __shared__ unsigned short P_lds[4][16][136];   // 17.4 KB
    const int bid = blockIdx.x;
    const int xcd = bid & 7;
    const int b   = xcd >> 1;
    const int idx = (bid >> 3) * 2 + (xcd & 1);   // [0,384)
    const int z    = idx & 7;
    const int xblk = idx >> 3;                    // [0,48)
    const int hz    = z >> 2;
    const int split = z & 3;
    const int n0 = seg[2*b] + xblk * 16;
    const int nend = seg[2*b + 1];
    if (n0 >= nend) return;
    const int nvalid = min(16, nend - n0);

    const int t = threadIdx.x;
    const int w = t >> 6, lane = t & 63;
    const int m16 = lane & 15, quad = lane >> 4;
    const int h = hz * 4 + w;

    int nq = n0 + m16; if (nq >= nend) nq = nend - 1;
    const unsigned short* qp = q_bf + (size_t)nq * HA + h * AA + quad * 8;
    const bf16x8 qa0 = *(const bf16x8*)qp;
    const bf16x8 qa1 = *(const bf16x8*)(qp + 32);

    const unsigned short* kb = k_blk + ((size_t)(b * HH + h)) * SS * 64;
    const unsigned short* vb = vT_bf + ((size_t)b * HA + h * AA) * SS;
    unsigned short (*Pw)[136] = P_lds[w];

    const bool do_logits = (hz == 0 && w == 0);
    bf16x8 qb0, qb1;
    const unsigned short* kb1 = k_blk + ((size_t)(b * HH + 1)) * SS * 64;
    if (do_logits) {
        const unsigned short* qp1 = q_bf + (size_t)nq * HA + AA + quad * 8;
        qb0 = *(const bf16x8*)qp1;
        qb1 = *(const bf16x8*)(qp1 + 32);
    }

    float m_s[4], l_s[4];
    #pragma unroll
    for (int r = 0; r < 4; ++r) { m_s[r] = -3.0e38f; l_s[r] = 0.f; }
    f32x4 facc[4];
    #pragma unroll
    for (int a = 0; a < 4; ++a) facc[a] = (f32x4){0.f, 0.f, 0.f, 0.f};

    for (int ch = 0; ch < 2; ++ch) {
        const int s0 = split * 256 + ch * 128;
        float msk[8];
        #pragma unroll
        for (int st = 0; st < 8; ++st)
            msk[st] = mask_f[b * SS + s0 + st * 16 + m16];
        // ---- phase A: QK^T (scaled raw scores in registers, C-layout) ----
        f32x4 d[8];
        #pragma unroll
        for (int st = 0; st < 8; ++st) {
            const unsigned short* kp = kb + (size_t)(s0 + st * 16 + m16) * 64 + quad * 8;
            const bf16x8 b0 = *(const bf16x8*)kp;
            const bf16x8 b1 = *(const bf16x8*)(kp + 32);
            f32x4 acc = (f32x4){0.f, 0.f, 0.f, 0.f};
            acc = __builtin_amdgcn_mfma_f32_16x16x32_bf16(qa0, b0, acc, 0, 0, 0);
            acc = __builtin_amdgcn_mfma_f32_16x16x32_bf16(qa1, b1, acc, 0, 0, 0);
            #pragma unroll
            for (int r = 0; r < 4; ++r) acc[r] *= 0.125f;
            d[st] = acc;
        }
        // ---- fused logits (wave h==0 of hz==0 blocks): + h1, write sum ----
        if (do_logits) {
            #pragma unroll
            for (int st = 0; st < 8; ++st) {
                const unsigned short* kp = kb1 + (size_t)(s0 + st * 16 + m16) * 64 + quad * 8;
                f32x4 acc = (f32x4){0.f, 0.f, 0.f, 0.f};
                acc = __builtin_amdgcn_mfma_f32_16x16x32_bf16(qb0, *(const bf16x8*)kp, acc, 0, 0, 0);
                acc = __builtin_amdgcn_mfma_f32_16x16x32_bf16(qb1, *(const bf16x8*)(kp + 32), acc, 0, 0, 0);
                #pragma unroll
                for (int r = 0; r < 4; ++r) {
                    const int node = quad * 4 + r;
                    if (node < nvalid)
                        out_logits[(size_t)(n0 + node) * SS + s0 + st * 16 + m16] =
                            d[st][r] + acc[r] * 0.125f;
                }
            }
        }
        // ---- register online masked softmax (row r in 16-lane group) ----
        float al[4];
        #pragma unroll
        for (int r = 0; r < 4; ++r) {
            float mx = -3.0e38f;
            #pragma unroll
            for (int st = 0; st < 8; ++st)
                mx = (msk[st] > 0.5f) ? fmaxf(mx, d[st][r]) : mx;
            mx = fmaxf(mx, __shfl_xor(mx, 1));
            mx = fmaxf(mx, __shfl_xor(mx, 2));
            mx = fmaxf(mx, __shfl_xor(mx, 4));
            mx = fmaxf(mx, __shfl_xor(mx, 8));
            const float mnew = fmaxf(m_s[r], mx);
            al[r] = __expf(m_s[r] - mnew);
            m_s[r] = mnew;
            float cs = 0.f;
            #pragma unroll
            for (int st = 0; st < 8; ++st) {
                const float e = (msk[st] > 0.5f) ? __expf(d[st][r] - mnew) : 0.f;
                d[st][r] = e;
                cs += e;
            }
            cs += __shfl_xor(cs, 1);
            cs += __shfl_xor(cs, 2);
            cs += __shfl_xor(cs, 4);
            cs += __shfl_xor(cs, 8);
            l_s[r] = l_s[r] * al[r] + cs;
        }
        // ---- P -> LDS (bf16, C-layout positions; wave-private slice) ----
        #pragma unroll
        for (int st = 0; st < 8; ++st)
            #pragma unroll
            for (int r = 0; r < 4; ++r)
                Pw[quad * 4 + r][st * 16 + m16] = f2bf(d[st][r]);
        // ---- phase C: PV accumulate (alpha rescale first) ----
        #pragma unroll
        for (int a = 0; a < 4; ++a)
            #pragma unroll
            for (int r = 0; r < 4; ++r) facc[a][r] *= al[r];
        #pragma unroll
        for (int sub = 0; sub < 4; ++sub) {
            const bf16x8 pa = *(const bf16x8*)&Pw[m16][sub * 32 + quad * 8];
            const unsigned short* vp0 = vb + (size_t)m16 * SS + s0 + sub * 32 + quad * 8;
            #pragma unroll
            for (int a = 0; a < 4; ++a) {
                const bf16x8 vfr = *(const bf16x8*)(vp0 + (size_t)(a * 16) * SS);
                facc[a] = __builtin_amdgcn_mfma_f32_16x16x32_bf16(pa, vfr, facc[a], 0, 0, 0);
            }
        }
    }
    // ---- epilogue: restage facc bf16 in LDS -> coalesced 2x16B stores ----
    #pragma unroll
    for (int a = 0; a < 4; ++a)
        #pragma unroll
        for (int r = 0; r < 4; ++r)
            Pw[quad * 4 + r][a * 16 + m16] = f2bf(facc[a][r]);
    {
        const int row = lane >> 2, cg = lane & 3;
        if (row < nvalid) {
            const uint4 v0 = *(const uint4*)&Pw[row][cg * 16];
            const uint4 v1 = *(const uint4*)&Pw[row][cg * 16 + 8];
            unsigned short* dst = part_O + (size_t)split * NND * HA +
                                  (size_t)(n0 + row) * HA + h * AA + cg * 16;
            *(uint4*)dst       = v0;
            *(uint4*)(dst + 8) = v1;
        }
    }
    if (m16 == 0) {
        #pragma unroll
        for (int r = 0; r < 4; ++r) {
            const int row = quad * 4 + r;
            if (row < nvalid)
                part_ml[(size_t)split * NND * HH + (size_t)(n0 + row) * HH + h] =
                    make_float2(m_s[r], l_s[r]);
        }
    }
}

// ---------------------------------------------------------------------------
// Kernel 4: fused combine(4 splits) + gate mul + Wback MFMA + residual + LN.
// 4 rows/block -> 512 blocks (2/CU).
// ---------------------------------------------------------------------------
__global__ __launch_bounds__(256) void back_ln_fused(
    const unsigned short* __restrict__ part_O, const float2* __restrict__ part_ml,
    const float* __restrict__ gate_ws, const unsigned short* __restrict__ WbackT,
    const float* __restrict__ x, const float* __restrict__ bback,
    const float* __restrict__ gamma, const float* __restrict__ beta,
    float* __restrict__ out)
{
    __shared__ float coef[NSPL][4][8];
    __shared__ unsigned short gf_l[4][520];
    __shared__ float nl[4][260];
    const int t = threadIdx.x, w = t >> 6, lane = t & 63;
    const int m16 = lane & 15, quad = lane >> 4;
    const int r0 = blockIdx.x * 4;
    if (t < 32) {
        const int row = t >> 3, h = t & 7, n = r0 + row;
        float2 ml[NSPL];
        #pragma unroll
        for (int s = 0; s < NSPL; ++s)
            ml[s] = part_ml[(size_t)s * NND * HH + (size_t)n * HH + h];
        float M = -3.0e38f;
        #pragma unroll
        for (int s = 0; s < NSPL; ++s) M = fmaxf(M, ml[s].x);
        float L = 0.f;
        float e[NSPL];
        #pragma unroll
        for (int s = 0; s < NSPL; ++s) { e[s] = __expf(ml[s].x - M); L += ml[s].y * e[s]; }
        const float invL = 1.f / (L + 1e-9f);
        #pragma unroll
        for (int s = 0; s < NSPL; ++s) coef[s][row][h] = e[s] * invL;
    }
    __syncthreads();
    #pragma unroll
    for (int it = 0; it < 2; ++it) {
        const int i = (t + it * 256) * 4;
        const int row = i >> 9, c = i & (HA - 1), h = c >> 6;
        const int n = r0 + row;
        float4 o = make_float4(0.f, 0.f, 0.f, 0.f);
        #pragma unroll
        for (int s = 0; s < NSPL; ++s) {
            const ushort4 p = *(const ushort4*)&part_O[(size_t)s * NND * HA + (size_t)n * HA + c];
            const float cf = coef[s][row][h];
            o.x = fmaf(bf2f(p.x), cf, o.x); o.y = fmaf(bf2f(p.y), cf, o.y);
            o.z = fmaf(bf2f(p.z), cf, o.z); o.w = fmaf(bf2f(p.w), cf, o.w);
        }
        const float4 g = *(const float4*)&gate_ws[(size_t)n * HA + c];
        ushort4 ob;
        ob.x = f2bf(g.x * o.x); ob.y = f2bf(g.y * o.y);
        ob.z = f2bf(g.z * o.z); ob.w = f2bf(g.w * o.w);
        *(ushort4*)&gf_l[row][c] = ob;
    }
    __syncthreads();
    bf16x8 af[16];
    #pragma unroll
    for (int j = 0; j < 16; ++j)
        af[j] = *(const bf16x8*)&gf_l[m16 & 3][quad * 8 + j * 32];
    #pragma unroll
    for (int nt = 0; nt < 4; ++nt) {
        const int n0 = w * 64 + nt * 16;
        const unsigned short* bp = WbackT + (size_t)(n0 + m16) * HA + quad * 8;
        f32x4 d = (f32x4){0.f, 0.f, 0.f, 0.f};
        #pragma unroll
        for (int j = 0; j < 16; ++j)
            d = __builtin_amdgcn_mfma_f32_16x16x32_bf16(af[j], *(const bf16x8*)(bp + j * 32), d, 0, 0, 0);
        const float bb = bback[n0 + m16];
        #pragma unroll
        for (int r = 0; r < 4; ++r) {
            const int rr = quad * 4 + r;
            if (rr < 4) nl[rr][n0 + m16] = d[r] + bb;
        }
    }
    __syncthreads();
    const int row = t >> 6, li = t & 63;
    const float* xr = x + (size_t)(r0 + row) * IFZ;
    float yv[4];
    float s1 = 0.f, s2 = 0.f;
    #pragma unroll
    for (int j = 0; j < 4; ++j) {
        const int c = li + j * 64;
        const float v = fmaf(1.41421356237309515f, xr[c], nl[row][c]);
        yv[j] = v; s1 += v; s2 += v * v;
    }
    #pragma unroll
    for (int off = 32; off >= 1; off >>= 1) {
        s1 += __shfl_xor(s1, off);
        s2 += __shfl_xor(s2, off);
    }
    const float mu  = s1 * (1.f / IFZ);
    const float var = s2 * (1.f / IFZ) - mu * mu;
    const float rv  = rsqrtf(var + 1e-5f);
    float* orow = out + (size_t)(r0 + row) * IFZ;
    #pragma unroll
    for (int j = 0; j < 4; ++j) {
        const int c = li + j * 64;
        orow[c] = (yv[j] - mu) * rv * gamma[c] + beta[c];
    }
}

extern "C" void kernel_launch(void* const* d_in, const int* in_sizes, int n_in,
                              void* d_out, int out_size, void* d_ws, size_t ws_size,
                              hipStream_t stream) {
    const float* x     = (const float*)d_in[0];
    const float* emb   = (const float*)d_in[1];
    const void*  mraw  = d_in[2];
    const void*  braw  = d_in[3];
    const float* Wq    = (const float*)d_in[4];
    const float* Wk    = (const float*)d_in[5];
    const float* Wv    = (const float*)d_in[6];
    const float* Wg    = (const float*)d_in[7];
    const float* bg    = (const float*)d_in[8];
    const float* Wback = (const float*)d_in[9];
    const float* bback = (const float*)d_in[10];
    const float* gamma = (const float*)d_in[11];
    const float* beta  = (const float*)d_in[12];

    char* ws = (char*)d_ws;
    const size_t MB = 1048576;
    size_t off = 0;
    float*          mask_f  = (float*)(ws + off);  off += 16384;
    int*            seg     = (int*)(ws + off);    off += 16384;
    unsigned short* WkT     = (unsigned short*)(ws + off); off += 393216;
    unsigned short* WvT     = (unsigned short*)(ws + off); off += 393216;
    unsigned short* WqT     = (unsigned short*)(ws + off); off += 262144;
    unsigned short* WgT     = (unsigned short*)(ws + off); off += 262144;
    unsigned short* WbackT  = (unsigned short*)(ws + off); off += 262144;
    unsigned short* k_blk   = (unsigned short*)(ws + off); off += 4*MB;
    unsigned short* vT_bf   = (unsigned short*)(ws + off); off += 4*MB;
    unsigned short* q_bf    = (unsigned short*)(ws + off); off += 2*MB;
    float*          gate_ws = (float*)(ws + off); off += 4*MB;
    unsigned short* part_O  = (unsigned short*)(ws + off); off += 8*MB;
    float2*         part_ml = (float2*)(ws + off); off += 524288;

    float* out        = (float*)d_out;
    float* out_logits = out + (size_t)NND * IFZ;

    hipLaunchKernelGGL(prep_kernel, dim3(193), dim3(256), 0, stream,
                       Wk, Wv, Wq, Wg, Wback, mraw, braw,
                       WkT, WvT, WqT, WgT, WbackT, mask_f, seg);
    hipLaunchKernelGGL(proj_mfma, dim3(1536), dim3(256), 0, stream,
                       emb, x, WkT, WvT, WqT, WgT, bg, k_blk, vT_bf, q_bf, gate_ws);
    hipLaunchKernelGGL(attn_kernel, dim3(BBATCH * NBX * 8), dim3(256), 0, stream,
                       k_blk, vT_bf, q_bf, mask_f, seg, part_O, part_ml, out_logits);
    hipLaunchKernelGGL(back_ln_fused, dim3(NND / 4), dim3(256), 0, stream,
                       part_O, part_ml, gate_ws, WbackT, x, bback, gamma, beta, out);
}

// Round 13
// 198.547 us; speedup vs baseline: 1.1138x; 1.1138x over previous
//
#include <hip/hip_runtime.h>
#include <hip/hip_bf16.h>

#define NND 2048
#define BBATCH 4
#define SS 1024
#define SFZ 384
#define IFZ 256
#define HH 8
#define AA 64
#define HA 512
#define NBX 48    // x-blocks per batch (768-node capacity, 13 sigma)
#define NSPL 8    // S-splits in attention

typedef __attribute__((ext_vector_type(8))) short bf16x8;
typedef __attribute__((ext_vector_type(4))) float f32x4;

__device__ __forceinline__ unsigned short f2bf(float f) {
    union { float f; unsigned u; } a; a.f = f;
    unsigned r = a.u + 0x7fffu + ((a.u >> 16) & 1u);
    return (unsigned short)(r >> 16);
}
__device__ __forceinline__ float bf2f(unsigned short u) {
    return __uint_as_float((unsigned)u << 16);
}

__device__ __forceinline__ bf16x8 cvt8(const float* __restrict__ p) {
    const float4 f0 = *(const float4*)p;
    const float4 f1 = *(const float4*)(p + 4);
    bf16x8 o;
    o[0] = (short)f2bf(f0.x); o[1] = (short)f2bf(f0.y);
    o[2] = (short)f2bf(f0.z); o[3] = (short)f2bf(f0.w);
    o[4] = (short)f2bf(f1.x); o[5] = (short)f2bf(f1.y);
    o[6] = (short)f2bf(f1.z); o[7] = (short)f2bf(f1.w);
    return o;
}

// ---------------------------------------------------------------------------
// Kernel P: prep. Blocks 0..191: weight transposes fp32->bf16.
// Block 192: detect mask/batch dtype -> mask_f, seg.
// ---------------------------------------------------------------------------
__device__ __forceinline__ void tile_transpose(
    const float* __restrict__ src, unsigned short* __restrict__ dst,
    int K, int N, int kt, int nt, int t)
{
    __shared__ unsigned short tile[64][65];
    const int k0 = kt * 64, n0 = nt * 64;
    const int tr = t >> 6, tc = t & 63;
    #pragma unroll
    for (int r = 0; r < 16; ++r)
        tile[tr + r*4][tc] = f2bf(src[(size_t)(k0 + tr + r*4) * N + n0 + tc]);
    __syncthreads();
    #pragma unroll
    for (int r = 0; r < 16; ++r)
        dst[(size_t)(n0 + tr + r*4) * K + k0 + tc] = tile[tc][tr + r*4];
}

__global__ __launch_bounds__(256) void prep_kernel(
    const float* __restrict__ Wk, const float* __restrict__ Wv,
    const float* __restrict__ Wq, const float* __restrict__ Wg,
    const float* __restrict__ Wback,
    const void* __restrict__ mask_raw, const void* __restrict__ batch_raw,
    unsigned short* __restrict__ WkT, unsigned short* __restrict__ WvT,
    unsigned short* __restrict__ WqT, unsigned short* __restrict__ WgT,
    unsigned short* __restrict__ WbackT,
    float* __restrict__ mask_f, int* __restrict__ seg)
{
    const int bx = blockIdx.x, t = threadIdx.x;
    if (bx < 48)  { tile_transpose(Wk, WkT, SFZ, HA, bx/8, bx%8, t); return; }
    if (bx < 96)  { const int i = bx-48;  tile_transpose(Wv, WvT, SFZ, HA, i/8, i%8, t); return; }
    if (bx < 128) { const int i = bx-96;  tile_transpose(Wq, WqT, IFZ, HA, i/8, i%8, t); return; }
    if (bx < 160) { const int i = bx-128; tile_transpose(Wg, WgT, IFZ, HA, i/8, i%8, t); return; }
    if (bx < 192) { const int i = bx-160; tile_transpose(Wback, WbackT, HA, IFZ, i/4, i%4, t); return; }
    __shared__ int fl[4];
    __shared__ int fb;
    __shared__ int cnt[4];
    if (t < 4) { fl[t] = 0; cnt[t] = 0; }
    if (t == 0) fb = 0;
    __syncthreads();
    const unsigned char*  mb = (const unsigned char*)mask_raw;
    const unsigned short* mh = (const unsigned short*)mask_raw;
    const unsigned int*   mw = (const unsigned int*)mask_raw;
    int f0 = 0, f1 = 0, f2 = 0, f3 = 0;
    for (int i = t; i < 2048; i += 256) {
        unsigned short h = mh[i];
        if (h == 0x3f80u) f0 = 1;
        if ((i & 1) == 0 && h != 0) f1 = 1;
    }
    for (int i = t; i < 4096; i += 256)
        if ((i & 3) != 0 && mb[i] != 0) f2 = 1;
    for (int i = t; i < 1024; i += 256)
        if ((i & 1) != 0 && mw[i] != 0) f3 = 1;
    const int* bw = (const int*)batch_raw;
    int f4 = 0;
    for (int i = t + 1; i < 2048; i += 256)
        if (bw[i] < bw[i-1]) f4 = 1;
    if (f0) atomicOr(&fl[0], 1);
    if (f1) atomicOr(&fl[1], 1);
    if (f2) atomicOr(&fl[2], 1);
    if (f3) atomicOr(&fl[3], 1);
    if (f4) atomicOr(&fb, 1);
    __syncthreads();
    int mode;
    if (fl[0])      mode = fl[1] ? 1 : 0;
    else if (fl[2]) mode = 2;
    else if (fl[3]) mode = 3;
    else            mode = 4;
    for (int s = t; s < BBATCH*SS; s += 256) {
        int m;
        switch (mode) {
            case 0:  m = (mw[s]   != 0); break;
            case 1:  m = (mh[s]   != 0); break;
            case 2:  m = (mb[s]   != 0); break;
            case 3:  m = (mw[s]   != 0); break;
            default: m = (mw[2*s] != 0); break;
        }
        mask_f[s] = m ? 1.0f : 0.0f;
    }
    const int b64 = fb;
    for (int i = t; i < NND; i += 256) {
        const int bv = (b64 ? bw[2*i] : bw[i]) & 3;
        atomicAdd(&cnt[bv], 1);
    }
    __syncthreads();
    if (t == 0) {
        int s = 0;
        for (int b = 0; b < 4; ++b) { seg[2*b] = s; s += cnt[b]; seg[2*b+1] = s; }
    }
}

// ---------------------------------------------------------------------------
// Kernel 1: fused MFMA projections. 1024 blocks:
// [0,512): k/v (r0=(bx>>1)*16, y=bx&1: 0->k head-major, 1->v -> in-kernel vT)
// [512,1024): q/gate (r0=(i>>2)*16, y=i&3: tensor=y>>1, col-half=y&1)
// ---------------------------------------------------------------------------
__global__ __launch_bounds__(256) void proj_mfma(
    const float* __restrict__ emb, const float* __restrict__ x,
    const unsigned short* __restrict__ WkT, const unsigned short* __restrict__ WvT,
    const unsigned short* __restrict__ WqT, const unsigned short* __restrict__ WgT,
    const float* __restrict__ bg,
    unsigned short* __restrict__ k_blk, unsigned short* __restrict__ vT_bf,
    unsigned short* __restrict__ q_bf, float* __restrict__ gate_ws)
{
    __shared__ unsigned short v_l[16][520];   // 16.6 KB (v-blocks only)
    const int t = threadIdx.x, w = t >> 6, lane = t & 63;
    const int m16 = lane & 15, quad = lane >> 4;
    const int bx = blockIdx.x;
    if (bx < 512) {
        const int r0 = (bx >> 1) * 16;
        const int b = r0 >> 10, srow = r0 & (SS - 1);
        const float* ap = emb + (size_t)(r0 + m16) * SFZ + quad * 8;
        bf16x8 af[12];
        #pragma unroll
        for (int j = 0; j < 12; ++j) af[j] = cvt8(ap + j * 32);
        if ((bx & 1) == 0) {
            #pragma unroll
            for (int nt = 0; nt < 8; ++nt) {
                const int n0 = w * 128 + nt * 16;
                const unsigned short* bp = WkT + (size_t)(n0 + m16) * SFZ + quad * 8;
                f32x4 d = (f32x4){0.f, 0.f, 0.f, 0.f};
                #pragma unroll
                for (int j = 0; j < 12; ++j)
                    d = __builtin_amdgcn_mfma_f32_16x16x32_bf16(af[j], *(const bf16x8*)(bp + j * 32), d, 0, 0, 0);
                const int head = n0 >> 6, coff = (n0 & 63) + m16;
                unsigned short* kb = k_blk + (((size_t)(b * HH + head)) * SS) * 64 + coff;
                #pragma unroll
                for (int r = 0; r < 4; ++r)
                    kb[(size_t)(srow + quad * 4 + r) * 64] = f2bf(d[r]);
            }
        } else {
            #pragma unroll
            for (int nt = 0; nt < 8; ++nt) {
                const int n0 = w * 128 + nt * 16;
                const unsigned short* bp = WvT + (size_t)(n0 + m16) * SFZ + quad * 8;
                f32x4 d = (f32x4){0.f, 0.f, 0.f, 0.f};
                #pragma unroll
                for (int j = 0; j < 12; ++j)
                    d = __builtin_amdgcn_mfma_f32_16x16x32_bf16(af[j], *(const bf16x8*)(bp + j * 32), d, 0, 0, 0);
                #pragma unroll
                for (int r = 0; r < 4; ++r)
                    v_l[quad * 4 + r][n0 + m16] = f2bf(d[r]);
            }
            __syncthreads();
            // vT[b][c][srow..srow+16): column gather from LDS, 2x16B stores
            for (int c = t; c < HA; c += 256) {
                unsigned short tmp[16];
                #pragma unroll
                for (int s = 0; s < 16; ++s) tmp[s] = v_l[s][c];
                unsigned short* dst = vT_bf + ((size_t)b * HA + c) * SS + srow;
                *(uint4*)dst       = ((const uint4*)tmp)[0];
                *(uint4*)(dst + 8) = ((const uint4*)tmp)[1];
            }
        }
    } else {
        const int i = bx - 512;
        const int r0 = (i >> 2) * 16;
        const int tensor = (i & 3) >> 1, half = i & 1;
        const unsigned short* Wt = tensor ? WgT : WqT;
        const float* ap = x + (size_t)(r0 + m16) * IFZ + quad * 8;
        bf16x8 af[8];
        #pragma unroll
        for (int j = 0; j < 8; ++j) af[j] = cvt8(ap + j * 32);
        #pragma unroll
        for (int nt = 0; nt < 4; ++nt) {
            const int n0 = half * 256 + w * 64 + nt * 16;
            const unsigned short* bp = Wt + (size_t)(n0 + m16) * IFZ + quad * 8;
            f32x4 d = (f32x4){0.f, 0.f, 0.f, 0.f};
            #pragma unroll
            for (int j = 0; j < 8; ++j)
                d = __builtin_amdgcn_mfma_f32_16x16x32_bf16(af[j], *(const bf16x8*)(bp + j * 32), d, 0, 0, 0);
            if (tensor == 0) {
                #pragma unroll
                for (int r = 0; r < 4; ++r)
                    q_bf[(size_t)(r0 + quad * 4 + r) * HA + n0 + m16] = f2bf(d[r]);
            } else {
                const float bgv = bg[n0 + m16];
                #pragma unroll
                for (int r = 0; r < 4; ++r)
                    gate_ws[(size_t)(r0 + quad * 4 + r) * HA + n0 + m16] =
                        1.f / (1.f + __expf(-(d[r] + bgv)));
            }
        }
    }
}

// ---------------------------------------------------------------------------
// Kernel 3: MFMA flash attention + fused raw-score logits.
// 1D grid 3072, XCD-batch affinity; idx -> (xblk, z); z = (hz, split of 8).
// Each wave: 1 head x 16 nodes x 128 s. hz==0 blocks also emit logits (h0+h1).
// ---------------------------------------------------------------------------
__global__ __launch_bounds__(256) void attn_kernel(
    const unsigned short* __restrict__ k_blk, const unsigned short* __restrict__ vT_bf,
    const unsigned short* __restrict__ q_bf, const float* __restrict__ mask_f,
    const int* __restrict__ seg, unsigned short* __restrict__ part_O,
    float2* __restrict__ part_ml, float* __restrict__ out_logits)
{
    __shared__ unsigned short P_lds[4][16][136];   // 17.4 KB
    __shared__ float raw[2][16][132];              // 16.9 KB (hz==0 logits stash)
    const int bid = blockIdx.x;
    const int xcd = bid & 7;
    const int b   = xcd >> 1;
    const int idx = (bid >> 3) * 2 + (xcd & 1);   // [0,768)
    const int z    = idx & 15;
    const int xblk = idx >> 4;                    // [0,48)
    const int hz    = z >> 3;
    const int split = z & 7;
    const int n0 = seg[2*b] + xblk * 16;
    const int nend = seg[2*b + 1];
    if (n0 >= nend) return;
    const int nvalid = min(16, nend - n0);

    const int t = threadIdx.x;
    const int w = t >> 6, lane = t & 63;
    const int m16 = lane & 15, quad = lane >> 4;
    const int h = hz * 4 + w;
    const int s0 = split * 128;

    int nq = n0 + m16; if (nq >= nend) nq = nend - 1;
    const unsigned short* qp = q_bf + (size_t)nq * HA + h * AA + quad * 8;
    const bf16x8 qa0 = *(const bf16x8*)qp;
    const bf16x8 qa1 = *(const bf16x8*)(qp + 32);

    const unsigned short* kb = k_blk + ((size_t)(b * HH + h)) * SS * 64;
    const unsigned short* vb = vT_bf + ((size_t)b * HA + h * AA) * SS;
    unsigned short (*Pw)[136] = P_lds[w];

    float msk[8];
    #pragma unroll
    for (int st = 0; st < 8; ++st)
        msk[st] = mask_f[b * SS + s0 + st * 16 + m16];

    // ---- phase A: QK^T (scaled raw scores in registers, C-layout) ----
    f32x4 d[8];
    #pragma unroll
    for (int st = 0; st < 8; ++st) {
        const unsigned short* kp = kb + (size_t)(s0 + st * 16 + m16) * 64 + quad * 8;
        const bf16x8 b0 = *(const bf16x8*)kp;
        const bf16x8 b1 = *(const bf16x8*)(kp + 32);
        f32x4 acc = (f32x4){0.f, 0.f, 0.f, 0.f};
        acc = __builtin_amdgcn_mfma_f32_16x16x32_bf16(qa0, b0, acc, 0, 0, 0);
        acc = __builtin_amdgcn_mfma_f32_16x16x32_bf16(qa1, b1, acc, 0, 0, 0);
        #pragma unroll
        for (int r = 0; r < 4; ++r) acc[r] *= 0.125f;
        d[st] = acc;
    }
    // ---- fused logits: heads 0,1 raw scores -> h0+h1 (hz==0 blocks) ----
    if (hz == 0) {
        if (w < 2) {
            #pragma unroll
            for (int st = 0; st < 8; ++st)
                #pragma unroll
                for (int r = 0; r < 4; ++r)
                    raw[w][quad * 4 + r][st * 16 + m16] = d[st][r];
        }
        __syncthreads();
        for (int i = t; i < 16 * 128; i += 256) {
            const int node = i >> 7, sp = i & 127;
            if (node < nvalid)
                out_logits[(size_t)(n0 + node) * SS + s0 + sp] =
                    raw[0][node][sp] + raw[1][node][sp];
        }
    }
    // ---- register masked softmax (single pass; row r in 16-lane group) ----
    float m_s[4], l_s[4];
    #pragma unroll
    for (int r = 0; r < 4; ++r) {
        float mx = -3.0e38f;
        #pragma unroll
        for (int st = 0; st < 8; ++st)
            mx = (msk[st] > 0.5f) ? fmaxf(mx, d[st][r]) : mx;
        mx = fmaxf(mx, __shfl_xor(mx, 1));
        mx = fmaxf(mx, __shfl_xor(mx, 2));
        mx = fmaxf(mx, __shfl_xor(mx, 4));
        mx = fmaxf(mx, __shfl_xor(mx, 8));
        m_s[r] = mx;
        float cs = 0.f;
        #pragma unroll
        for (int st = 0; st < 8; ++st) {
            const float e = (msk[st] > 0.5f) ? __expf(d[st][r] - mx) : 0.f;
            d[st][r] = e;
            cs += e;
        }
        cs += __shfl_xor(cs, 1);
        cs += __shfl_xor(cs, 2);
        cs += __shfl_xor(cs, 4);
        cs += __shfl_xor(cs, 8);
        l_s[r] = cs;
    }
    // ---- P -> LDS (bf16, C-layout positions) ----
    #pragma unroll
    for (int st = 0; st < 8; ++st)
        #pragma unroll
        for (int r = 0; r < 4; ++r)
            Pw[quad * 4 + r][st * 16 + m16] = f2bf(d[st][r]);
    // ---- phase C: PV accumulate ----
    f32x4 facc[4];
    #pragma unroll
    for (int a = 0; a < 4; ++a) facc[a] = (f32x4){0.f, 0.f, 0.f, 0.f};
    #pragma unroll
    for (int sub = 0; sub < 4; ++sub) {
        const bf16x8 pa = *(const bf16x8*)&Pw[m16][sub * 32 + quad * 8];
        const unsigned short* vp0 = vb + (size_t)m16 * SS + s0 + sub * 32 + quad * 8;
        #pragma unroll
        for (int a = 0; a < 4; ++a) {
            const bf16x8 vfr = *(const bf16x8*)(vp0 + (size_t)(a * 16) * SS);
            facc[a] = __builtin_amdgcn_mfma_f32_16x16x32_bf16(pa, vfr, facc[a], 0, 0, 0);
        }
    }
    // ---- epilogue: bf16 unnormalized partial O + (m,l) ----
    unsigned short* po = part_O + (size_t)split * NND * HA;
    #pragma unroll
    for (int a = 0; a < 4; ++a)
        #pragma unroll
        for (int r = 0; r < 4; ++r) {
            const int row = quad * 4 + r;
            if (row < nvalid)
                po[(size_t)(n0 + row) * HA + h * AA + a * 16 + m16] = f2bf(facc[a][r]);
        }
    if (m16 == 0) {
        #pragma unroll
        for (int r = 0; r < 4; ++r) {
            const int row = quad * 4 + r;
            if (row < nvalid)
                part_ml[(size_t)split * NND * HH + (size_t)(n0 + row) * HH + h] =
                    make_float2(m_s[r], l_s[r]);
        }
    }
}

// ---------------------------------------------------------------------------
// Kernel 4: fused combine(8 splits) + gate mul + Wback MFMA + residual + LN.
// 8 rows/block -> 256 blocks.
// ---------------------------------------------------------------------------
__global__ __launch_bounds__(256) void back_ln_fused(
    const unsigned short* __restrict__ part_O, const float2* __restrict__ part_ml,
    const float* __restrict__ gate_ws, const unsigned short* __restrict__ WbackT,
    const float* __restrict__ x, const float* __restrict__ bback,
    const float* __restrict__ gamma, const float* __restrict__ beta,
    float* __restrict__ out)
{
    __shared__ float coef[NSPL][8][8];
    __shared__ unsigned short gf_l[8][520];
    __shared__ float nl[8][260];
    const int t = threadIdx.x, w = t >> 6, lane = t & 63;
    const int m16 = lane & 15, quad = lane >> 4;
    const int r0 = blockIdx.x * 8;
    if (t < 64) {
        const int row = t >> 3, h = t & 7, n = r0 + row;
        float2 ml[NSPL];
        #pragma unroll
        for (int s = 0; s < NSPL; ++s)
            ml[s] = part_ml[(size_t)s * NND * HH + (size_t)n * HH + h];
        float M = -3.0e38f;
        #pragma unroll
        for (int s = 0; s < NSPL; ++s) M = fmaxf(M, ml[s].x);
        float L = 0.f;
        float e[NSPL];
        #pragma unroll
        for (int s = 0; s < NSPL; ++s) { e[s] = __expf(ml[s].x - M); L += ml[s].y * e[s]; }
        const float invL = 1.f / (L + 1e-9f);
        #pragma unroll
        for (int s = 0; s < NSPL; ++s) coef[s][row][h] = e[s] * invL;
    }
    __syncthreads();
    #pragma unroll
    for (int it = 0; it < 4; ++it) {
        const int i = (t + it * 256) * 4;
        const int row = i >> 9, c = i & (HA - 1), h = c >> 6;
        const int n = r0 + row;
        float4 o = make_float4(0.f, 0.f, 0.f, 0.f);
        #pragma unroll
        for (int s = 0; s < NSPL; ++s) {
            const ushort4 p = *(const ushort4*)&part_O[(size_t)s * NND * HA + (size_t)n * HA + c];
            const float cf = coef[s][row][h];
            o.x = fmaf(bf2f(p.x), cf, o.x); o.y = fmaf(bf2f(p.y), cf, o.y);
            o.z = fmaf(bf2f(p.z), cf, o.z); o.w = fmaf(bf2f(p.w), cf, o.w);
        }
        const float4 g = *(const float4*)&gate_ws[(size_t)n * HA + c];
        ushort4 ob;
        ob.x = f2bf(g.x * o.x); ob.y = f2bf(g.y * o.y);
        ob.z = f2bf(g.z * o.z); ob.w = f2bf(g.w * o.w);
        *(ushort4*)&gf_l[row][c] = ob;
    }
    __syncthreads();
    bf16x8 af[16];
    #pragma unroll
    for (int j = 0; j < 16; ++j)
        af[j] = *(const bf16x8*)&gf_l[m16 & 7][quad * 8 + j * 32];
    #pragma unroll
    for (int nt = 0; nt < 4; ++nt) {
        const int n0 = w * 64 + nt * 16;
        const unsigned short* bp = WbackT + (size_t)(n0 + m16) * HA + quad * 8;
        f32x4 d = (f32x4){0.f, 0.f, 0.f, 0.f};
        #pragma unroll
        for (int j = 0; j < 16; ++j)
            d = __builtin_amdgcn_mfma_f32_16x16x32_bf16(af[j], *(const bf16x8*)(bp + j * 32), d, 0, 0, 0);
        const float bb = bback[n0 + m16];
        #pragma unroll
        for (int r = 0; r < 4; ++r) {
            const int rr = quad * 4 + r;
            if (rr < 8) nl[rr][n0 + m16] = d[r] + bb;
        }
    }
    __syncthreads();
    const int row = t >> 5, li = t & 31;
    const float* xr = x + (size_t)(r0 + row) * IFZ;
    float yv[8];
    float s1 = 0.f, s2 = 0.f;
    #pragma unroll
    for (int j = 0; j < 8; ++j) {
        const int c = li + j * 32;
        const float v = fmaf(1.41421356237309515f, xr[c], nl[row][c]);
        yv[j] = v; s1 += v; s2 += v * v;
    }
    #pragma unroll
    for (int off = 16; off >= 1; off >>= 1) {
        s1 += __shfl_xor(s1, off);
        s2 += __shfl_xor(s2, off);
    }
    const float mu  = s1 * (1.f / IFZ);
    const float var = s2 * (1.f / IFZ) - mu * mu;
    const float rv  = rsqrtf(var + 1e-5f);
    float* orow = out + (size_t)(r0 + row) * IFZ;
    #pragma unroll
    for (int j = 0; j < 8; ++j) {
        const int c = li + j * 32;
        orow[c] = (yv[j] - mu) * rv * gamma[c] + beta[c];
    }
}

extern "C" void kernel_launch(void* const* d_in, const int* in_sizes, int n_in,
                              void* d_out, int out_size, void* d_ws, size_t ws_size,
                              hipStream_t stream) {
    const float* x     = (const float*)d_in[0];
    const float* emb   = (const float*)d_in[1];
    const void*  mraw  = d_in[2];
    const void*  braw  = d_in[3];
    const float* Wq    = (const float*)d_in[4];
    const float* Wk    = (const float*)d_in[5];
    const float* Wv    = (const float*)d_in[6];
    const float* Wg    = (const float*)d_in[7];
    const float* bg    = (const float*)d_in[8];
    const float* Wback = (const float*)d_in[9];
    const float* bback = (const float*)d_in[10];
    const float* gamma = (const float*)d_in[11];
    const float* beta  = (const float*)d_in[12];

    char* ws = (char*)d_ws;
    const size_t MB = 1048576;
    size_t off = 0;
    float*          mask_f  = (float*)(ws + off);  off += 16384;
    int*            seg     = (int*)(ws + off);    off += 16384;
    unsigned short* WkT     = (unsigned short*)(ws + off); off += 393216;
    unsigned short* WvT     = (unsigned short*)(ws + off); off += 393216;
    unsigned short* WqT     = (unsigned short*)(ws + off); off += 262144;
    unsigned short* WgT     = (unsigned short*)(ws + off); off += 262144;
    unsigned short* WbackT  = (unsigned short*)(ws + off); off += 262144;
    unsigned short* k_blk   = (unsigned short*)(ws + off); off += 4*MB;
    unsigned short* vT_bf   = (unsigned short*)(ws + off); off += 4*MB;
    unsigned short* q_bf    = (unsigned short*)(ws + off); off += 2*MB;
    float*          gate_ws = (float*)(ws + off); off += 4*MB;
    unsigned short* part_O  = (unsigned short*)(ws + off); off += 16*MB;
    float2*         part_ml = (float2*)(ws + off); off += 1*MB;

    float* out        = (float*)d_out;
    float* out_logits = out + (size_t)NND * IFZ;

    hipLaunchKernelGGL(prep_kernel, dim3(193), dim3(256), 0, stream,
                       Wk, Wv, Wq, Wg, Wback, mraw, braw,
                       WkT, WvT, WqT, WgT, WbackT, mask_f, seg);
    hipLaunchKernelGGL(proj_mfma, dim3(1024), dim3(256), 0, stream,
                       emb, x, WkT, WvT, WqT, WgT, bg, k_blk, vT_bf, q_bf, gate_ws);
    hipLaunchKernelGGL(attn_kernel, dim3(BBATCH * NBX * 16), dim3(256), 0, stream,
                       k_blk, vT_bf, q_bf, mask_f, seg, part_O, part_ml, out_logits);
    hipLaunchKernelGGL(back_ln_fused, dim3(NND / 8), dim3(256), 0, stream,
                       part_O, part_ml, gate_ws, WbackT, x, bback, gamma, beta, out);
}